// Round 9
// baseline (1118.952 us; speedup 1.0000x reference)
//
#include <hip/hip_runtime.h>
#include <hip/hip_fp16.h>

// ---------------------------------------------------------------------------
// MSHGAT forward, round 9:
//  - CSR build rewritten as two-phase LDS-staged binning:
//      segcount (1 streaming pass) -> bin (LDS buckets, coalesced run writes)
//      -> hist_runs -> scan -> place_runs (per-seg, XCD-L2-resident)
//    replaces the 8x-rescan hist_all/place_all (R8 postmortem: nt-loads do
//    NOT stop L2 eviction of partially-filled write lines; 86MB writeback
//    for 7.6MB payload).
//  - NTL reverted (measured regression).
// N=50000, D=64, E=600000, NNZ=800000.
// ---------------------------------------------------------------------------

#define SEGSH 13      // seg = key >> 13 (keyspan 8192, 7 used segs of 8)
#define NSEG 8
#define BINBLK 768    // bin kernel blocks (3/CU at 41KB LDS)
#define SBLK 64       // blocks per seg for hist_runs/place_runs
#define SCHUNK 1024   // elements per scan block; PB = ceil(N/1024) <= 64

// ---- phase A1: per-seg entry counts (one streaming pass) -------------------
__global__ __launch_bounds__(256) void segcount_kernel(const int* __restrict__ dst, int e,
                                                       const int* __restrict__ row,
                                                       const int* __restrict__ col, int nnz,
                                                       int* __restrict__ segcnt) {  // [24]
    __shared__ int lc[24];
    if (threadIdx.x < 24) lc[threadIdx.x] = 0;
    __syncthreads();
    int i0 = blockIdx.x * 256 + threadIdx.x;
    int stride = gridDim.x * 256;
    for (int i = i0; i < e; i += stride) atomicAdd(&lc[dst[i] >> SEGSH], 1);
    for (int i = i0; i < nnz; i += stride) {
        atomicAdd(&lc[8 + (col[i] >> SEGSH)], 1);
        atomicAdd(&lc[16 + (row[i] >> SEGSH)], 1);
    }
    __syncthreads();
    if (threadIdx.x < 24 && lc[threadIdx.x] > 0) atomicAdd(&segcnt[threadIdx.x], lc[threadIdx.x]);
}

// ---- phase A2: bin entries into per-seg runs (LDS-staged, coalesced) -------
__global__ __launch_bounds__(256) void bin_kernel(const int* __restrict__ src,
                                                  const int* __restrict__ dst, int e,
                                                  const int* __restrict__ row,
                                                  const int* __restrict__ col,
                                                  const float* __restrict__ val, int nnz,
                                                  const int* __restrict__ segcnt,
                                                  int* __restrict__ gcur,          // [24], zeroed
                                                  unsigned* __restrict__ runG,
                                                  uint2* __restrict__ runC,
                                                  uint2* __restrict__ runR) {
    __shared__ unsigned sG[NSEG][256];
    __shared__ uint2 sC[NSEG][256];
    __shared__ uint2 sR[NSEG][256];
    __shared__ int cnt[3][NSEG];
    __shared__ unsigned base0[3][NSEG];
    if (threadIdx.x < 24) {
        int st = threadIdx.x >> 3, s = threadIdx.x & 7;
        unsigned b = 0;
        for (int k = 0; k < s; ++k) b += (unsigned)segcnt[st * 8 + k];
        base0[st][s] = b;
        cnt[st][s & 7] = 0;
    }
    __syncthreads();
    int wv = threadIdx.x >> 6, ln = threadIdx.x & 63;

    // --- G stream (gcn edges) ---
    int iters = (e + BINBLK * 256 - 1) / (BINBLK * 256);
    for (int it = 0; it < iters; ++it) {
        int i = (it * BINBLK + blockIdx.x) * 256 + threadIdx.x;
        if (i < e) {
            int d = dst[i], s = src[i];
            int sg = d >> SEGSH;
            int p = atomicAdd(&cnt[0][sg], 1);
            sG[sg][p] = ((unsigned)d << 16) | (unsigned)s;
        }
        __syncthreads();
        for (int s = wv * 2; s < wv * 2 + 2; ++s) {     // wave w -> segs 2w,2w+1
            int c = cnt[0][s];
            if (c > 0) {
                int b = 0;
                if (ln == 0) b = atomicAdd(&gcur[s], c);
                b = __shfl(b, 0, 64);
                unsigned gb = base0[0][s] + (unsigned)b;
                for (int k = ln; k < c; k += 64) runG[gb + k] = sG[s][k];
            }
        }
        __syncthreads();
        if (threadIdx.x < 8) cnt[0][threadIdx.x] = 0;
        __syncthreads();
    }

    // --- C/R streams (hypergraph nnz) ---
    iters = (nnz + BINBLK * 256 - 1) / (BINBLK * 256);
    for (int it = 0; it < iters; ++it) {
        int i = (it * BINBLK + blockIdx.x) * 256 + threadIdx.x;
        if (i < nnz) {
            int r = row[i], c = col[i];
            unsigned hv = (unsigned)__half_as_ushort(__float2half(val[i]));
            int sgc = c >> SEGSH;
            int p = atomicAdd(&cnt[1][sgc], 1);
            sC[sgc][p] = make_uint2((unsigned)c, ((unsigned)r << 16) | hv);
            int sgr = r >> SEGSH;
            p = atomicAdd(&cnt[2][sgr], 1);
            sR[sgr][p] = make_uint2((unsigned)r, ((unsigned)c << 16) | hv);
        }
        __syncthreads();
        for (int q = 0; q < 4; ++q) {                   // wave w -> buckets 4w..4w+3
            int idx = wv * 4 + q;                       // 0..15
            int st = 1 + (idx >> 3), s = idx & 7;
            int c = cnt[st][s];
            if (c > 0) {
                int b = 0;
                if (ln == 0) b = atomicAdd(&gcur[st * 8 + s], c);
                b = __shfl(b, 0, 64);
                unsigned gb = base0[st][s] + (unsigned)b;
                uint2* dp = (st == 1) ? runC : runR;
                const uint2* sp = (st == 1) ? sC[s] : sR[s];
                for (int k = ln; k < c; k += 64) dp[gb + k] = sp[k];
            }
        }
        __syncthreads();
        if (threadIdx.x < 16) cnt[1 + (threadIdx.x >> 3)][threadIdx.x & 7] = 0;
        __syncthreads();
    }
}

// ---- phase B1: per-key histogram from seg runs (XCD-local) -----------------
__global__ __launch_bounds__(256) void hist_runs_kernel(const unsigned* __restrict__ runG,
                                                        const uint2* __restrict__ runC,
                                                        const uint2* __restrict__ runR,
                                                        const int* __restrict__ segcnt,
                                                        int* __restrict__ cg,
                                                        int* __restrict__ cc,
                                                        int* __restrict__ cr) {
    int seg = blockIdx.x & 7, blk = blockIdx.x >> 3;
    const int stride = SBLK * 256;
    int bG = 0, bC = 0, bR = 0;
    for (int k = 0; k < seg; ++k) { bG += segcnt[k]; bC += segcnt[8 + k]; bR += segcnt[16 + k]; }
    int nG = segcnt[seg], nC = segcnt[8 + seg], nR = segcnt[16 + seg];
    int t0 = blk * 256 + threadIdx.x;
    for (int i = t0; i < nG; i += stride) atomicAdd(&cg[runG[bG + i] >> 16], 1);
    for (int i = t0; i < nC; i += stride) atomicAdd(&cc[runC[bC + i].x], 1);
    for (int i = t0; i < nR; i += stride) atomicAdd(&cr[runR[bR + i].x], 1);
}

// ---- two-phase decoupled scan (3 arrays) ------------------------------------
__global__ __launch_bounds__(256) void scan_part_kernel(const int* __restrict__ g_cnt,
                                                        const int* __restrict__ c_cnt,
                                                        const int* __restrict__ r_cnt,
                                                        int* __restrict__ partials,
                                                        int n, int pb) {
    int which = blockIdx.x / pb, blk = blockIdx.x % pb;
    const int* cnt = (which == 0) ? g_cnt : (which == 1) ? c_cnt : r_cnt;
    int i0 = blk * SCHUNK + threadIdx.x * 4;
    int4 v = make_int4(0, 0, 0, 0);
    if (i0 + 3 < n) v = *(const int4*)(cnt + i0);
    else {
        if (i0 < n)     v.x = cnt[i0];
        if (i0 + 1 < n) v.y = cnt[i0 + 1];
        if (i0 + 2 < n) v.z = cnt[i0 + 2];
    }
    int s = v.x + v.y + v.z + v.w;
    __shared__ int red[256];
    red[threadIdx.x] = s;
    __syncthreads();
    for (int d = 128; d; d >>= 1) {
        if (threadIdx.x < d) red[threadIdx.x] += red[threadIdx.x + d];
        __syncthreads();
    }
    if (threadIdx.x == 0) partials[blockIdx.x] = red[0];
}

__global__ __launch_bounds__(256) void scan_apply_kernel(int* __restrict__ g_cnt, int* __restrict__ g_off,
                                                         int* __restrict__ c_cnt, int* __restrict__ c_off,
                                                         int* __restrict__ r_cnt, int* __restrict__ r_off,
                                                         const int* __restrict__ partials,
                                                         float* __restrict__ dinv, int n, int pb) {
    int which = blockIdx.x / pb, blk = blockIdx.x % pb;
    int* cnt = (which == 0) ? g_cnt : (which == 1) ? c_cnt : r_cnt;
    int* off = (which == 0) ? g_off : (which == 1) ? c_off : r_off;
    __shared__ int sbase, stotal;
    __shared__ int sc[256];
    int tid = threadIdx.x;
    if (tid < 64) {
        int p = (tid < pb) ? partials[which * pb + tid] : 0;
        int pre = (tid < blk) ? p : 0;
        int tot = p;
        for (int d = 32; d; d >>= 1) {
            pre += __shfl_xor(pre, d, 64);
            tot += __shfl_xor(tot, d, 64);
        }
        if (tid == 0) { sbase = pre; stotal = tot; }
    }
    int i0 = blk * SCHUNK + tid * 4;
    int4 v = make_int4(0, 0, 0, 0);
    if (i0 + 3 < n) v = *(const int4*)(cnt + i0);
    else {
        if (i0 < n)     v.x = cnt[i0];
        if (i0 + 1 < n) v.y = cnt[i0 + 1];
        if (i0 + 2 < n) v.z = cnt[i0 + 2];
    }
    int s = v.x + v.y + v.z + v.w;
    sc[tid] = s;
    __syncthreads();
    for (int d = 1; d < 256; d <<= 1) {
        int t = (tid >= d) ? sc[tid - d] : 0;
        __syncthreads();
        sc[tid] += t;
        __syncthreads();
    }
    int run = sbase + sc[tid] - s;   // exclusive prefix
    int cv[4] = {v.x, v.y, v.z, v.w};
#pragma unroll
    for (int k = 0; k < 4; ++k) {
        int i = i0 + k;
        if (i < n) {
            off[i] = run;
            if (which == 0) dinv[i] = rsqrtf((float)(cv[k] + 1));
            cnt[i] = run;   // becomes "cur" for placement
            run += cv[k];
        }
    }
    if (blk == 0 && tid == 0) off[n] = stotal;
}

// ---- phase B2: place from seg runs into CSR (XCD-local r/w working set) -----
__global__ __launch_bounds__(256) void place_runs_kernel(const unsigned* __restrict__ runG,
                                                         const uint2* __restrict__ runC,
                                                         const uint2* __restrict__ runR,
                                                         const int* __restrict__ segcnt,
                                                         int* __restrict__ curg,
                                                         int* __restrict__ curc,
                                                         int* __restrict__ curr,
                                                         unsigned short* __restrict__ gsrcs,
                                                         unsigned* __restrict__ entc,
                                                         unsigned* __restrict__ entr) {
    int seg = blockIdx.x & 7, blk = blockIdx.x >> 3;
    const int stride = SBLK * 256;
    int bG = 0, bC = 0, bR = 0;
    for (int k = 0; k < seg; ++k) { bG += segcnt[k]; bC += segcnt[8 + k]; bR += segcnt[16 + k]; }
    int nG = segcnt[seg], nC = segcnt[8 + seg], nR = segcnt[16 + seg];
    int t0 = blk * 256 + threadIdx.x;
    for (int i = t0; i < nG; i += stride) {
        unsigned t = runG[bG + i];
        int pos = atomicAdd(&curg[t >> 16], 1);
        gsrcs[pos] = (unsigned short)(t & 0xffffu);
    }
    for (int i = t0; i < nC; i += stride) {
        uint2 t = runC[bC + i];
        int pos = atomicAdd(&curc[t.x], 1);
        entc[pos] = t.y;
    }
    for (int i = t0; i < nR; i += stride) {
        uint2 t = runR[bR + i];
        int pos = atomicAdd(&curr[t.x], 1);
        entr[pos] = t.y;
    }
}

// ---- weight precompute: W12 = W1@W2 (64x64), bw = b1@W2 (64) ----------------
__global__ __launch_bounds__(64) void wprep_kernel(const float* __restrict__ W1,  // 64x128
                                                   const float* __restrict__ W2,  // 128x64
                                                   const float* __restrict__ b1,  // 128
                                                   float* __restrict__ W12,
                                                   float* __restrict__ bw) {
    int r = blockIdx.x;
    int c = threadIdx.x;
    const float* a = (r < 64) ? (W1 + r * 128) : b1;
    float acc = 0.f;
#pragma unroll 8
    for (int k = 0; k < 128; ++k) acc = fmaf(a[k], W2[k * 64 + c], acc);
    if (r < 64) W12[r * 64 + c] = acc;
    else bw[c] = acc;
}

// ---- GCN gather (normalized) ------------------------------------------------
template <bool SDI>
__global__ __launch_bounds__(256) void gcn_gather_kernel(const float* __restrict__ x,
                                                         const float* __restrict__ dinv,
                                                         const int* __restrict__ off,
                                                         const unsigned short* __restrict__ srcs,
                                                         float* __restrict__ out,
                                                         float* __restrict__ sdi, int n) {
    int node = blockIdx.x * 4 + (threadIdx.x >> 6);
    if (node >= n) return;
    int lane = threadIdx.x & 63;
    int sub = lane >> 4;
    int q = lane & 15;
    int e0 = off[node], e1 = off[node + 1];
    float4 acc = make_float4(0.f, 0.f, 0.f, 0.f);
    float dsum = 0.f;
    int e = e0 + sub;
    int s = (e < e1) ? (int)srcs[e] : 0;
    float ds = (e < e1) ? dinv[s] : 0.f;
    for (; e < e1; e += 4) {
        int sn = (e + 4 < e1) ? (int)srcs[e + 4] : 0;
        float dsn = (e + 4 < e1) ? dinv[sn] : 0.f;
        const float4 v = *(const float4*)(x + (long long)s * 64 + q * 4);
        acc.x = fmaf(ds, v.x, acc.x);
        acc.y = fmaf(ds, v.y, acc.y);
        acc.z = fmaf(ds, v.z, acc.z);
        acc.w = fmaf(ds, v.w, acc.w);
        dsum += ds;
        s = sn; ds = dsn;
    }
    acc.x += __shfl_xor(acc.x, 16, 64); acc.x += __shfl_xor(acc.x, 32, 64);
    acc.y += __shfl_xor(acc.y, 16, 64); acc.y += __shfl_xor(acc.y, 32, 64);
    acc.z += __shfl_xor(acc.z, 16, 64); acc.z += __shfl_xor(acc.z, 32, 64);
    acc.w += __shfl_xor(acc.w, 16, 64); acc.w += __shfl_xor(acc.w, 32, 64);
    if (SDI) { dsum += __shfl_xor(dsum, 16, 64); dsum += __shfl_xor(dsum, 32, 64); }
    if (sub == 0) {
        float dt = dinv[node];
        const float4 xs = *(const float4*)(x + (long long)node * 64 + q * 4);
        float4 o;
        o.x = dt * fmaf(dt, xs.x, acc.x);
        o.y = dt * fmaf(dt, xs.y, acc.y);
        o.z = dt * fmaf(dt, xs.z, acc.z);
        o.w = dt * fmaf(dt, xs.w, acc.w);
        *(float4*)(out + (long long)node * 64 + q * 4) = o;
        if (SDI && q == 0) sdi[node] = dt * (dt + dsum);
    }
}

// ---- GEMM h2 = u @ W12 + sdi[r]*bw + b2, fused BN-stats accumulation -------
__global__ __launch_bounds__(256) void gemm_h2_kernel(const float* __restrict__ X,
                                                      const float* __restrict__ W12,
                                                      const float* __restrict__ bw,
                                                      const float* __restrict__ b2,
                                                      const float* __restrict__ sdi,
                                                      float* __restrict__ h2,
                                                      float* __restrict__ stats, int n) {
    __shared__ float Wl[64 * 64];
    __shared__ float cadd[64], b2l[64];
    __shared__ float ls[4][64], ls2[4][64];
    for (int i = threadIdx.x; i < 4096; i += 256) Wl[i] = W12[i];
    if (threadIdx.x < 64) cadd[threadIdx.x] = bw[threadIdx.x];
    else if (threadIdx.x < 128) b2l[threadIdx.x - 64] = b2[threadIdx.x - 64];
    __syncthreads();
    int m = threadIdx.x & 63;
    int g = threadIdx.x >> 6;
    float sl = 0.f, s2l = 0.f;
    int rend = (blockIdx.x + 1) * 32; if (rend > n) rend = n;
    for (int r = blockIdx.x * 32 + g; r < rend; r += 4) {
        const float* xr = X + (long long)r * 64;
        float acc = 0.0f;
#pragma unroll 8
        for (int k = 0; k < 64; ++k) acc = fmaf(xr[k], Wl[k * 64 + m], acc);
        float v = acc + sdi[r] * cadd[m] + b2l[m];
        h2[(long long)r * 64 + m] = v;
        sl += v; s2l += v * v;
    }
    ls[g][m] = sl; ls2[g][m] = s2l;
    __syncthreads();
    if (g == 0) {
        float s  = ls[0][m] + ls[1][m] + ls[2][m] + ls[3][m];
        float s2 = ls2[0][m] + ls2[1][m] + ls2[2][m] + ls2[3][m];
        atomicAdd(&stats[m], s);
        atomicAdd(&stats[64 + m], s2);
    }
}

// ---- HGNN gather; BN=true applies bn+relu+hgc1_bias to gathered rows --------
template <bool BN>
__global__ __launch_bounds__(256) void hg_gather_kernel(const float* __restrict__ in,
                                                        const int* __restrict__ off,
                                                        const unsigned* __restrict__ ents,
                                                        const float* __restrict__ stats,
                                                        const float* __restrict__ gamma,
                                                        const float* __restrict__ beta,
                                                        const float* __restrict__ hbias,
                                                        float invN,
                                                        float* __restrict__ out, int n) {
    int node = blockIdx.x * 4 + (threadIdx.x >> 6);
    if (node >= n) return;
    int lane = threadIdx.x & 63;
    int sub = lane >> 4;
    int q = lane & 15;
    float sc[4], sh[4], hb[4];
    if (BN) {
#pragma unroll
        for (int c = 0; c < 4; ++c) {
            int col = q * 4 + c;
            float mu = stats[col] * invN;
            float var = stats[64 + col] * invN - mu * mu;
            float s = gamma[col] * rsqrtf(var + 1e-5f);
            sc[c] = s; sh[c] = beta[col] - mu * s; hb[c] = hbias[col];
        }
    }
    int e0 = off[node], e1 = off[node + 1];
    float4 acc = make_float4(0.f, 0.f, 0.f, 0.f);
    int e = e0 + sub;
    unsigned t = (e < e1) ? ents[e] : 0u;
    for (; e < e1; e += 4) {
        unsigned tn = (e + 4 < e1) ? ents[e + 4] : 0u;
        float vv = __half2float(__ushort_as_half((unsigned short)(t & 0xffffu)));
        float4 v = *(const float4*)(in + (long long)(t >> 16) * 64 + q * 4);
        if (BN) {
            v.x = fmaxf(fmaf(v.x, sc[0], sh[0]), 0.f) + hb[0];
            v.y = fmaxf(fmaf(v.y, sc[1], sh[1]), 0.f) + hb[1];
            v.z = fmaxf(fmaf(v.z, sc[2], sh[2]), 0.f) + hb[2];
            v.w = fmaxf(fmaf(v.w, sc[3], sh[3]), 0.f) + hb[3];
        }
        acc.x = fmaf(vv, v.x, acc.x);
        acc.y = fmaf(vv, v.y, acc.y);
        acc.z = fmaf(vv, v.z, acc.z);
        acc.w = fmaf(vv, v.w, acc.w);
        t = tn;
    }
    acc.x += __shfl_xor(acc.x, 16, 64); acc.x += __shfl_xor(acc.x, 32, 64);
    acc.y += __shfl_xor(acc.y, 16, 64); acc.y += __shfl_xor(acc.y, 32, 64);
    acc.z += __shfl_xor(acc.z, 16, 64); acc.z += __shfl_xor(acc.z, 32, 64);
    acc.w += __shfl_xor(acc.w, 16, 64); acc.w += __shfl_xor(acc.w, 32, 64);
    if (sub == 0) *(float4*)(out + (long long)node * 64 + q * 4) = acc;
}

// ---- fused tail: softmax -> fc1 -> fusion gate; bn applied to hidden --------
#define TPAD 68
__device__ __forceinline__ float dot4(float4 a, float4 b) {
    return fmaf(a.x, b.x, fmaf(a.y, b.y, fmaf(a.z, b.z, a.w * b.w)));
}

__global__ __launch_bounds__(256) void tail_kernel(const float* __restrict__ x2,
                                                   const float* __restrict__ h2raw,
                                                   const float* __restrict__ fc1_W,
                                                   const float* __restrict__ fusW1,
                                                   const float* __restrict__ b1,
                                                   const float* __restrict__ w2,
                                                   const float* __restrict__ b2,
                                                   const float* __restrict__ stats,
                                                   const float* __restrict__ gamma,
                                                   const float* __restrict__ beta,
                                                   float invN,
                                                   float* __restrict__ out, int n) {
    __shared__ float A[64 * TPAD];    // P (softmax probs), later S (subn)
    __shared__ float Hs[64 * TPAD];   // hidden tile (bn applied)
    __shared__ float WL[64 * TPAD];   // fc1_W, later fus_l1_W
    __shared__ float bsc[64], bsh[64];
    int t = threadIdx.x;
    int tx = t & 15, ty = t >> 4;
    int r0 = blockIdx.x * 64;

    if (t < 64) {
        float mu = stats[t] * invN;
        float var = stats[64 + t] * invN - mu * mu;
        float s = gamma[t] * rsqrtf(var + 1e-5f);
        bsc[t] = s; bsh[t] = beta[t] - mu * s;
    }
    __syncthreads();

    float b1d[4], w2d[4];
#pragma unroll
    for (int di = 0; di < 4; ++di) {
        b1d[di] = b1[tx + 16 * di];
        w2d[di] = w2[tx + 16 * di];
    }
    float b20 = b2[0];

    for (int f = t; f < 1024; f += 256) {
        int d = f >> 4, k4 = (f & 15) << 2;
        *(float4*)&WL[d * TPAD + k4] = *(const float4*)&fc1_W[d * 64 + k4];
        int gr = r0 + d;
        float4 hv = make_float4(0.f, 0.f, 0.f, 0.f);
        if (gr < n) {
            hv = *(const float4*)&h2raw[(long long)gr * 64 + k4];
            hv.x = fmaf(hv.x, bsc[k4],     bsh[k4]);
            hv.y = fmaf(hv.y, bsc[k4 + 1], bsh[k4 + 1]);
            hv.z = fmaf(hv.z, bsc[k4 + 2], bsh[k4 + 2]);
            hv.w = fmaf(hv.w, bsc[k4 + 3], bsh[k4 + 3]);
        }
        *(float4*)&Hs[d * TPAD + k4] = hv;
    }

#pragma unroll
    for (int ri = 0; ri < 4; ++ri) {
        int rl = 4 * ty + ri;
        int r = r0 + rl;
        bool ok = r < n;
        float vv[4];
#pragma unroll
        for (int di = 0; di < 4; ++di)
            vv[di] = ok ? x2[(long long)r * 64 + tx + 16 * di] : 0.f;
        float m = fmaxf(fmaxf(vv[0], vv[1]), fmaxf(vv[2], vv[3]));
        for (int s = 1; s < 16; s <<= 1) m = fmaxf(m, __shfl_xor(m, s, 16));
        float e0 = expf(vv[0] - m), e1 = expf(vv[1] - m);
        float e2 = expf(vv[2] - m), e3 = expf(vv[3] - m);
        float sm = e0 + e1 + e2 + e3;
        for (int s = 1; s < 16; s <<= 1) sm += __shfl_xor(sm, s, 16);
        float inv = 1.0f / sm;
        A[rl * TPAD + tx]      = e0 * inv;
        A[rl * TPAD + tx + 16] = e1 * inv;
        A[rl * TPAD + tx + 32] = e2 * inv;
        A[rl * TPAD + tx + 48] = e3 * inv;
    }
    __syncthreads();

    float sn[4][4];
#pragma unroll
    for (int ri = 0; ri < 4; ++ri)
#pragma unroll
        for (int di = 0; di < 4; ++di) sn[ri][di] = 0.f;
    for (int k = 0; k < 64; k += 4) {
        float4 p4[4], w4[4];
#pragma unroll
        for (int ri = 0; ri < 4; ++ri) p4[ri] = *(float4*)&A[(4 * ty + ri) * TPAD + k];
#pragma unroll
        for (int di = 0; di < 4; ++di) w4[di] = *(float4*)&WL[(tx + 16 * di) * TPAD + k];
#pragma unroll
        for (int ri = 0; ri < 4; ++ri)
#pragma unroll
            for (int di = 0; di < 4; ++di)
                sn[ri][di] += dot4(p4[ri], w4[di]);
    }
    __syncthreads();

#pragma unroll
    for (int ri = 0; ri < 4; ++ri)
#pragma unroll
        for (int di = 0; di < 4; ++di)
            A[(4 * ty + ri) * TPAD + tx + 16 * di] = sn[ri][di];
    for (int f = t; f < 1024; f += 256) {
        int d = f >> 4, k4 = (f & 15) << 2;
        *(float4*)&WL[d * TPAD + k4] = *(const float4*)&fusW1[d * 64 + k4];
    }
    __syncthreads();

    float aH[4][4], aS[4][4];
#pragma unroll
    for (int ri = 0; ri < 4; ++ri)
#pragma unroll
        for (int di = 0; di < 4; ++di) { aH[ri][di] = b1d[di]; aS[ri][di] = b1d[di]; }
    for (int k = 0; k < 64; k += 4) {
        float4 h4[4], s4[4], w4[4];
#pragma unroll
        for (int ri = 0; ri < 4; ++ri) {
            h4[ri] = *(float4*)&Hs[(4 * ty + ri) * TPAD + k];
            s4[ri] = *(float4*)&A[(4 * ty + ri) * TPAD + k];
        }
#pragma unroll
        for (int di = 0; di < 4; ++di) w4[di] = *(float4*)&WL[(tx + 16 * di) * TPAD + k];
#pragma unroll
        for (int ri = 0; ri < 4; ++ri)
#pragma unroll
            for (int di = 0; di < 4; ++di) {
                aH[ri][di] += dot4(h4[ri], w4[di]);
                aS[ri][di] += dot4(s4[ri], w4[di]);
            }
    }

#pragma unroll
    for (int ri = 0; ri < 4; ++ri) {
        int rl = 4 * ty + ri;
        int r = r0 + rl;
        float pH = 0.f, pS = 0.f;
#pragma unroll
        for (int di = 0; di < 4; ++di) {
            pH = fmaf(tanhf(aH[ri][di]), w2d[di], pH);
            pS = fmaf(tanhf(aS[ri][di]), w2d[di], pS);
        }
        for (int s = 1; s < 16; s <<= 1) {
            pH += __shfl_xor(pH, s, 16);
            pS += __shfl_xor(pS, s, 16);
        }
        pH += b20; pS += b20;
        float mx = fmaxf(pH, pS);
        float eH = expf(pH - mx), eS = expf(pS - mx);
        float inv = 1.0f / (eH + eS);
        if (r < n) {
#pragma unroll
            for (int di = 0; di < 4; ++di) {
                int d = tx + 16 * di;
                float hv = Hs[rl * TPAD + d];
                out[(long long)r * 64 + d] = (eH * hv + eS * sn[ri][di]) * inv;
            }
        }
    }
}

// ---------------------------------------------------------------------------
extern "C" void kernel_launch(void* const* d_in, const int* in_sizes, int n_in,
                              void* d_out, int out_size, void* d_ws, size_t ws_size,
                              hipStream_t stream) {
    const float* emb       = (const float*)d_in[0];
    const float* W1        = (const float*)d_in[1];
    const float* b1        = (const float*)d_in[2];
    const float* W2        = (const float*)d_in[3];
    const float* b2        = (const float*)d_in[4];
    const float* gamma     = (const float*)d_in[5];
    const float* beta      = (const float*)d_in[6];
    const float* hgc1_bias = (const float*)d_in[7];
    const float* fc1_W     = (const float*)d_in[8];
    const float* fus_l1_W  = (const float*)d_in[9];
    const float* fus_l1_b  = (const float*)d_in[10];
    const float* fus_l2_W  = (const float*)d_in[11];
    const float* fus_l2_b  = (const float*)d_in[12];
    const float* hg_val    = (const float*)d_in[13];
    const int*   edge_index= (const int*)d_in[14];
    const int*   hg_row    = (const int*)d_in[15];
    const int*   hg_col    = (const int*)d_in[16];

    const int N   = in_sizes[0] / 64;
    const int E   = in_sizes[14] / 2;
    const int NNZ = in_sizes[13];
    const int Np  = (N + 3) & ~3;            // 16B-aligned strides
    const int PB = (N + SCHUNK - 1) / SCHUNK;   // scan blocks per array (<=64)
    const int* src = edge_index;
    const int* dst = edge_index + E;

    // workspace layout (4B units):
    // dinv Np | sdi Np | w12 4096 | bw 64 |
    // Z: [stats 128 | segcnt 24 | gcur 24 | gcn_cnt Np | hgc_cnt Np | hgr_cnt Np]
    // gcn_off Np+4 | hgc_off Np+4 | hgr_off Np+4 | partials 192 |
    // gcn_srcs E/2(u16) | hgc_ent NNZ | hgr_ent NNZ | buf1 128*Np | buf2 64*Np
    // runs (runG E | runC 2*NNZ | runR 2*NNZ) alias buf1 (dead until gathers)
    float* ws      = (float*)d_ws;
    float* dinv    = ws;
    float* sdi     = dinv + Np;
    float* w12     = sdi + Np;
    float* bw      = w12 + 4096;
    float* stats   = bw + 64;
    int*   segcnt  = (int*)(stats + 128);
    int*   gcur    = segcnt + 24;
    int*   gcn_cnt = gcur + 24;
    int*   hgc_cnt = gcn_cnt + Np;
    int*   hgr_cnt = hgc_cnt + Np;
    int*   gcn_off = hgr_cnt + Np;
    int*   hgc_off = gcn_off + (Np + 4);
    int*   hgr_off = hgc_off + (Np + 4);
    int*   partials= hgr_off + (Np + 4);
    unsigned short* gcn_srcs = (unsigned short*)(partials + 192);
    unsigned* hgc_ent = (unsigned*)(gcn_srcs + ((E + 1) & ~1));
    unsigned* hgr_ent = hgc_ent + NNZ;
    float* buf1    = (float*)(hgr_ent + NNZ);
    float* buf2    = buf1 + (size_t)128 * Np;

    // runs alias buf1 (dead until gcn_gather #2 writes ubuf)
    const int Ep = (E + 1) & ~1;
    unsigned* runG = (unsigned*)buf1;
    uint2*    runC = (uint2*)(runG + Ep);
    uint2*    runR = runC + NNZ;

    float* tbuf = buf2;                      // A-hat emb        N x 64
    float* ubuf = buf1;                      // A-hat^2 emb      N x 64
    float* h2   = buf1 + (size_t)64 * Np;    // raw h2 (pre-bn)  N x 64
    float* eemb = buf2;                      // edge emb         N x 64 (tbuf dead)
    float* x2   = buf1;                      // HGNN out         N x 64 (ubuf dead)
    float* out  = (float*)d_out;

    const float invN = 1.0f / (float)N;

    // --- CSR build: segcount -> bin -> hist_runs -> scan -> place_runs ---
    hipMemsetAsync(stats, 0, (size_t)(128 + 48 + 3 * Np) * sizeof(int), stream);
    segcount_kernel<<<512, 256, 0, stream>>>(dst, E, hg_row, hg_col, NNZ, segcnt);
    bin_kernel<<<BINBLK, 256, 0, stream>>>(src, dst, E, hg_row, hg_col, hg_val, NNZ,
                                           segcnt, gcur, runG, runC, runR);
    hist_runs_kernel<<<8 * SBLK, 256, 0, stream>>>(runG, runC, runR, segcnt,
                                                   gcn_cnt, hgc_cnt, hgr_cnt);
    scan_part_kernel<<<3 * PB, 256, 0, stream>>>(gcn_cnt, hgc_cnt, hgr_cnt, partials, N, PB);
    scan_apply_kernel<<<3 * PB, 256, 0, stream>>>(gcn_cnt, gcn_off, hgc_cnt, hgc_off,
                                                  hgr_cnt, hgr_off, partials, dinv, N, PB);
    place_runs_kernel<<<8 * SBLK, 256, 0, stream>>>(runG, runC, runR, segcnt,
                                                    gcn_cnt, hgc_cnt, hgr_cnt,
                                                    gcn_srcs, hgc_ent, hgr_ent);

    // --- weight precompute + reassociated GCN ---
    wprep_kernel<<<65, 64, 0, stream>>>(W1, W2, b1, w12, bw);
    gcn_gather_kernel<true><<<(N + 3) / 4, 256, 0, stream>>>(emb, dinv, gcn_off, gcn_srcs,
                                                             tbuf, sdi, N);
    gcn_gather_kernel<false><<<(N + 3) / 4, 256, 0, stream>>>(tbuf, dinv, gcn_off, gcn_srcs,
                                                              ubuf, nullptr, N);
    gemm_h2_kernel<<<(N + 31) / 32, 256, 0, stream>>>(ubuf, w12, bw, b2, sdi, h2, stats, N);

    // --- HGNN: edge_emb = G^T relu(bn(h2))+bias ; x2 = G edge_emb ---
    hg_gather_kernel<true><<<(N + 3) / 4, 256, 0, stream>>>(h2, hgc_off, hgc_ent,
                                                            stats, gamma, beta, hgc1_bias,
                                                            invN, eemb, N);
    hg_gather_kernel<false><<<(N + 3) / 4, 256, 0, stream>>>(eemb, hgr_off, hgr_ent,
                                                             nullptr, nullptr, nullptr, nullptr,
                                                             0.f, x2, N);

    // --- fused softmax + fc1 + fusion gate (bn on hidden inline) ---
    tail_kernel<<<(N + 63) / 64, 256, 0, stream>>>(x2, h2, fc1_W, fus_l1_W, fus_l1_b,
                                                   fus_l2_W, fus_l2_b, stats, gamma, beta,
                                                   invN, out, N);
}

// Round 10
// 443.221 us; speedup vs baseline: 2.5246x; 2.5246x over previous
//
#include <hip/hip_runtime.h>
#include <hip/hip_fp16.h>

// ---------------------------------------------------------------------------
// MSHGAT forward, round 10:
//  - CSR build reverted to R7 (segmented hist/place, two-phase scan; R9's
//    LDS-binning serialized on global run cursors; R8's NTL was a regression)
//  - fp16-packed gather operands: emb16 / tbuf16 / xre16 / eemb16 halve the
//    ~720MB of random row reads in the 4 gather kernels
//  - gemm_h2 keeps fused BN-stats; bn_apply16 materializes relu(bn)+bias fp16
// N=50000, D=64, E=600000, NNZ=800000.
// ---------------------------------------------------------------------------

#define SEGS 8
#define SEGBLK 128   // blocks per segment for hist/place
#define SCHUNK 1024  // elements per scan block; PB = ceil(N/1024) <= 64

// ---- segmented histograms (gcn by dst, hg by row and by col) ---------------
__global__ __launch_bounds__(256) void hist_all_kernel(const int* __restrict__ dst, int e,
                                                       const int* __restrict__ row,
                                                       const int* __restrict__ col, int nnz,
                                                       int* __restrict__ cg,
                                                       int* __restrict__ cr,
                                                       int* __restrict__ cc, int keyspan) {
    int seg = blockIdx.x & (SEGS - 1);
    int klo = seg * keyspan, khi = klo + keyspan;
    int base = (blockIdx.x >> 3) * 256 + threadIdx.x;
    const int stride = SEGBLK * 256;
    for (int i = base; i < e; i += stride) {
        int d = dst[i];
        if (d >= klo && d < khi) atomicAdd(&cg[d], 1);
    }
    for (int i = base; i < nnz; i += stride) {
        int r = row[i];
        if (r >= klo && r < khi) atomicAdd(&cr[r], 1);
        int c = col[i];
        if (c >= klo && c < khi) atomicAdd(&cc[c], 1);
    }
}

// ---- two-phase decoupled scan (3 arrays) ------------------------------------
__global__ __launch_bounds__(256) void scan_part_kernel(const int* __restrict__ g_cnt,
                                                        const int* __restrict__ c_cnt,
                                                        const int* __restrict__ r_cnt,
                                                        int* __restrict__ partials,
                                                        int n, int pb) {
    int which = blockIdx.x / pb, blk = blockIdx.x % pb;
    const int* cnt = (which == 0) ? g_cnt : (which == 1) ? c_cnt : r_cnt;
    int i0 = blk * SCHUNK + threadIdx.x * 4;
    int4 v = make_int4(0, 0, 0, 0);
    if (i0 + 3 < n) v = *(const int4*)(cnt + i0);
    else {
        if (i0 < n)     v.x = cnt[i0];
        if (i0 + 1 < n) v.y = cnt[i0 + 1];
        if (i0 + 2 < n) v.z = cnt[i0 + 2];
    }
    int s = v.x + v.y + v.z + v.w;
    __shared__ int red[256];
    red[threadIdx.x] = s;
    __syncthreads();
    for (int d = 128; d; d >>= 1) {
        if (threadIdx.x < d) red[threadIdx.x] += red[threadIdx.x + d];
        __syncthreads();
    }
    if (threadIdx.x == 0) partials[blockIdx.x] = red[0];
}

__global__ __launch_bounds__(256) void scan_apply_kernel(int* __restrict__ g_cnt, int* __restrict__ g_off,
                                                         int* __restrict__ c_cnt, int* __restrict__ c_off,
                                                         int* __restrict__ r_cnt, int* __restrict__ r_off,
                                                         const int* __restrict__ partials,
                                                         float* __restrict__ dinv, int n, int pb) {
    int which = blockIdx.x / pb, blk = blockIdx.x % pb;
    int* cnt = (which == 0) ? g_cnt : (which == 1) ? c_cnt : r_cnt;
    int* off = (which == 0) ? g_off : (which == 1) ? c_off : r_off;
    __shared__ int sbase, stotal;
    __shared__ int sc[256];
    int tid = threadIdx.x;
    if (tid < 64) {
        int p = (tid < pb) ? partials[which * pb + tid] : 0;
        int pre = (tid < blk) ? p : 0;
        int tot = p;
        for (int d = 32; d; d >>= 1) {
            pre += __shfl_xor(pre, d, 64);
            tot += __shfl_xor(tot, d, 64);
        }
        if (tid == 0) { sbase = pre; stotal = tot; }
    }
    int i0 = blk * SCHUNK + tid * 4;
    int4 v = make_int4(0, 0, 0, 0);
    if (i0 + 3 < n) v = *(const int4*)(cnt + i0);
    else {
        if (i0 < n)     v.x = cnt[i0];
        if (i0 + 1 < n) v.y = cnt[i0 + 1];
        if (i0 + 2 < n) v.z = cnt[i0 + 2];
    }
    int s = v.x + v.y + v.z + v.w;
    sc[tid] = s;
    __syncthreads();
    for (int d = 1; d < 256; d <<= 1) {
        int t = (tid >= d) ? sc[tid - d] : 0;
        __syncthreads();
        sc[tid] += t;
        __syncthreads();
    }
    int run = sbase + sc[tid] - s;   // exclusive prefix
    int cv[4] = {v.x, v.y, v.z, v.w};
#pragma unroll
    for (int k = 0; k < 4; ++k) {
        int i = i0 + k;
        if (i < n) {
            off[i] = run;
            if (which == 0) dinv[i] = rsqrtf((float)(cv[k] + 1));
            cnt[i] = run;   // becomes "cur" for placement
            run += cv[k];
        }
    }
    if (blk == 0 && tid == 0) off[n] = stotal;
}

// ---- segmented placement (gcn srcs u16 + packed hg entries) -----------------
__global__ __launch_bounds__(256) void place_all_kernel(const int* __restrict__ src,
                                                        const int* __restrict__ dst,
                                                        int* __restrict__ gcur,
                                                        unsigned short* __restrict__ gsrcs, int e,
                                                        const int* __restrict__ row,
                                                        const int* __restrict__ col,
                                                        const float* __restrict__ val,
                                                        int* __restrict__ curc,
                                                        int* __restrict__ curr,
                                                        unsigned* __restrict__ entc,
                                                        unsigned* __restrict__ entr, int nnz,
                                                        int keyspan) {
    int seg = blockIdx.x & (SEGS - 1);
    int klo = seg * keyspan, khi = klo + keyspan;
    int base = (blockIdx.x >> 3) * 256 + threadIdx.x;
    const int stride = SEGBLK * 256;
    for (int i = base; i < e; i += stride) {
        int d = dst[i];
        if (d >= klo && d < khi) {
            int pos = atomicAdd(&gcur[d], 1);
            gsrcs[pos] = (unsigned short)src[i];
        }
    }
    for (int i = base; i < nnz; i += stride) {
        int r = row[i], c = col[i];
        bool inc = (c >= klo && c < khi);
        bool inr = (r >= klo && r < khi);
        if (inc || inr) {
            unsigned hv = (unsigned)__half_as_ushort(__float2half(val[i]));
            if (inc) {
                int pc = atomicAdd(&curc[c], 1);
                entc[pc] = ((unsigned)r << 16) | hv;    // CSR by col: (row, val)
            }
            if (inr) {
                int pr = atomicAdd(&curr[r], 1);
                entr[pr] = ((unsigned)c << 16) | hv;    // CSR by row: (col, val)
            }
        }
    }
}

// ---- weight precompute: W12 = W1@W2 (64x64), bw = b1@W2 (64) ----------------
__global__ __launch_bounds__(64) void wprep_kernel(const float* __restrict__ W1,  // 64x128
                                                   const float* __restrict__ W2,  // 128x64
                                                   const float* __restrict__ b1,  // 128
                                                   float* __restrict__ W12,
                                                   float* __restrict__ bw) {
    int r = blockIdx.x;
    int c = threadIdx.x;
    const float* a = (r < 64) ? (W1 + r * 128) : b1;
    float acc = 0.f;
#pragma unroll 8
    for (int k = 0; k < 128; ++k) acc = fmaf(a[k], W2[k * 64 + c], acc);
    if (r < 64) W12[r * 64 + c] = acc;
    else bw[c] = acc;
}

// ---- f32 -> f16 row cast (emb16) --------------------------------------------
__global__ __launch_bounds__(256) void conv16_kernel(const float* __restrict__ in,
                                                     __half* __restrict__ out, int total4) {
    int tid = blockIdx.x * 256 + threadIdx.x;
    if (tid >= total4) return;
    const float4 v = *(const float4*)(in + tid * 4);
    __half2 a = __float22half2_rn(make_float2(v.x, v.y));
    __half2 b = __float22half2_rn(make_float2(v.z, v.w));
    uint2 w;
    w.x = *(unsigned*)&a; w.y = *(unsigned*)&b;
    *(uint2*)(out + tid * 4) = w;
}

// ---- GCN gather on fp16 rows:
// out_i = dinv_i * (dinv_i * x_i + sum_e dinv_s * x_s)
// OUT16: write fp16 row; SDI: also sdi_i = dinv_i*(dinv_i + sum dinv_s)
template <bool SDI, bool OUT16>
__global__ __launch_bounds__(256) void gcn_gather16_kernel(const __half* __restrict__ x,
                                                           const float* __restrict__ dinv,
                                                           const int* __restrict__ off,
                                                           const unsigned short* __restrict__ srcs,
                                                           __half* __restrict__ out16,
                                                           float* __restrict__ out32,
                                                           float* __restrict__ sdi, int n) {
    int node = blockIdx.x * 4 + (threadIdx.x >> 6);
    if (node >= n) return;
    int lane = threadIdx.x & 63;
    int sub = lane >> 4;
    int q = lane & 15;
    int e0 = off[node], e1 = off[node + 1];
    float4 acc = make_float4(0.f, 0.f, 0.f, 0.f);
    float dsum = 0.f;
    int e = e0 + sub;
    int s = (e < e1) ? (int)srcs[e] : 0;
    float ds = (e < e1) ? dinv[s] : 0.f;
    for (; e < e1; e += 4) {
        int sn = (e + 4 < e1) ? (int)srcs[e + 4] : 0;
        float dsn = (e + 4 < e1) ? dinv[sn] : 0.f;
        uint2 u = ((const uint2*)(x + (long long)s * 64))[q];
        float2 f0 = __half22float2(*(__half2*)&u.x);
        float2 f1 = __half22float2(*(__half2*)&u.y);
        acc.x = fmaf(ds, f0.x, acc.x);
        acc.y = fmaf(ds, f0.y, acc.y);
        acc.z = fmaf(ds, f1.x, acc.z);
        acc.w = fmaf(ds, f1.y, acc.w);
        dsum += ds;
        s = sn; ds = dsn;
    }
    acc.x += __shfl_xor(acc.x, 16, 64); acc.x += __shfl_xor(acc.x, 32, 64);
    acc.y += __shfl_xor(acc.y, 16, 64); acc.y += __shfl_xor(acc.y, 32, 64);
    acc.z += __shfl_xor(acc.z, 16, 64); acc.z += __shfl_xor(acc.z, 32, 64);
    acc.w += __shfl_xor(acc.w, 16, 64); acc.w += __shfl_xor(acc.w, 32, 64);
    if (SDI) { dsum += __shfl_xor(dsum, 16, 64); dsum += __shfl_xor(dsum, 32, 64); }
    if (sub == 0) {
        float dt = dinv[node];
        uint2 u = ((const uint2*)(x + (long long)node * 64))[q];
        float2 f0 = __half22float2(*(__half2*)&u.x);
        float2 f1 = __half22float2(*(__half2*)&u.y);
        float4 o;
        o.x = dt * fmaf(dt, f0.x, acc.x);
        o.y = dt * fmaf(dt, f0.y, acc.y);
        o.z = dt * fmaf(dt, f1.x, acc.z);
        o.w = dt * fmaf(dt, f1.y, acc.w);
        if (OUT16) {
            __half2 a = __float22half2_rn(make_float2(o.x, o.y));
            __half2 b = __float22half2_rn(make_float2(o.z, o.w));
            uint2 w; w.x = *(unsigned*)&a; w.y = *(unsigned*)&b;
            ((uint2*)(out16 + (long long)node * 64))[q] = w;
        } else {
            *(float4*)(out32 + (long long)node * 64 + q * 4) = o;
        }
        if (SDI && q == 0) sdi[node] = dt * (dt + dsum);
    }
}

// ---- GEMM h2 = u @ W12 + sdi[r]*bw + b2, fused BN-stats accumulation -------
__global__ __launch_bounds__(256) void gemm_h2_kernel(const float* __restrict__ X,
                                                      const float* __restrict__ W12,
                                                      const float* __restrict__ bw,
                                                      const float* __restrict__ b2,
                                                      const float* __restrict__ sdi,
                                                      float* __restrict__ h2,
                                                      float* __restrict__ stats, int n) {
    __shared__ float Wl[64 * 64];
    __shared__ float cadd[64], b2l[64];
    __shared__ float ls[4][64], ls2[4][64];
    for (int i = threadIdx.x; i < 4096; i += 256) Wl[i] = W12[i];
    if (threadIdx.x < 64) cadd[threadIdx.x] = bw[threadIdx.x];
    else if (threadIdx.x < 128) b2l[threadIdx.x - 64] = b2[threadIdx.x - 64];
    __syncthreads();
    int m = threadIdx.x & 63;
    int g = threadIdx.x >> 6;
    float sl = 0.f, s2l = 0.f;
    int rend = (blockIdx.x + 1) * 32; if (rend > n) rend = n;
    for (int r = blockIdx.x * 32 + g; r < rend; r += 4) {
        const float* xr = X + (long long)r * 64;
        float acc = 0.0f;
#pragma unroll 8
        for (int k = 0; k < 64; ++k) acc = fmaf(xr[k], Wl[k * 64 + m], acc);
        float v = acc + sdi[r] * cadd[m] + b2l[m];
        h2[(long long)r * 64 + m] = v;
        sl += v; s2l += v * v;
    }
    ls[g][m] = sl; ls2[g][m] = s2l;
    __syncthreads();
    if (g == 0) {
        float s  = ls[0][m] + ls[1][m] + ls[2][m] + ls[3][m];
        float s2 = ls2[0][m] + ls2[1][m] + ls2[2][m] + ls2[3][m];
        atomicAdd(&stats[m], s);
        atomicAdd(&stats[64 + m], s2);
    }
}

// ---- bn+relu+hgc1_bias -> fp16 (xre16) ---------------------------------------
__global__ __launch_bounds__(256) void bn_apply16_kernel(const float* __restrict__ h2,
                                                         const float* __restrict__ stats,
                                                         const float* __restrict__ gamma,
                                                         const float* __restrict__ beta,
                                                         const float* __restrict__ hbias,
                                                         float invN,
                                                         __half* __restrict__ xre, int total4) {
    __shared__ float bsc[64], bsh[64], hbl[64];
    int t = threadIdx.x;
    if (t < 64) {
        float mu = stats[t] * invN;
        float var = stats[64 + t] * invN - mu * mu;
        float s = gamma[t] * rsqrtf(var + 1e-5f);
        bsc[t] = s; bsh[t] = beta[t] - mu * s; hbl[t] = hbias[t];
    }
    __syncthreads();
    int tid = blockIdx.x * 256 + t;
    if (tid >= total4) return;
    int base = tid * 4;
    int c0 = base & 63;
    const float4 v = *(const float4*)(h2 + base);
    float o0 = fmaxf(fmaf(v.x, bsc[c0],     bsh[c0]),     0.f) + hbl[c0];
    float o1 = fmaxf(fmaf(v.y, bsc[c0 + 1], bsh[c0 + 1]), 0.f) + hbl[c0 + 1];
    float o2 = fmaxf(fmaf(v.z, bsc[c0 + 2], bsh[c0 + 2]), 0.f) + hbl[c0 + 2];
    float o3 = fmaxf(fmaf(v.w, bsc[c0 + 3], bsh[c0 + 3]), 0.f) + hbl[c0 + 3];
    __half2 a = __float22half2_rn(make_float2(o0, o1));
    __half2 b = __float22half2_rn(make_float2(o2, o3));
    uint2 w; w.x = *(unsigned*)&a; w.y = *(unsigned*)&b;
    *(uint2*)(xre + base) = w;
}

// ---- HGNN gather on fp16 rows: out = sum val_e * in[idx_e] -------------------
template <bool OUT16>
__global__ __launch_bounds__(256) void hg_gather16_kernel(const __half* __restrict__ in,
                                                          const int* __restrict__ off,
                                                          const unsigned* __restrict__ ents,
                                                          __half* __restrict__ out16,
                                                          float* __restrict__ out32, int n) {
    int node = blockIdx.x * 4 + (threadIdx.x >> 6);
    if (node >= n) return;
    int lane = threadIdx.x & 63;
    int sub = lane >> 4;
    int q = lane & 15;
    int e0 = off[node], e1 = off[node + 1];
    float4 acc = make_float4(0.f, 0.f, 0.f, 0.f);
    int e = e0 + sub;
    unsigned t = (e < e1) ? ents[e] : 0u;
    for (; e < e1; e += 4) {
        unsigned tn = (e + 4 < e1) ? ents[e + 4] : 0u;
        float vv = __half2float(__ushort_as_half((unsigned short)(t & 0xffffu)));
        uint2 u = ((const uint2*)(in + (long long)(t >> 16) * 64))[q];
        float2 f0 = __half22float2(*(__half2*)&u.x);
        float2 f1 = __half22float2(*(__half2*)&u.y);
        acc.x = fmaf(vv, f0.x, acc.x);
        acc.y = fmaf(vv, f0.y, acc.y);
        acc.z = fmaf(vv, f1.x, acc.z);
        acc.w = fmaf(vv, f1.y, acc.w);
        t = tn;
    }
    acc.x += __shfl_xor(acc.x, 16, 64); acc.x += __shfl_xor(acc.x, 32, 64);
    acc.y += __shfl_xor(acc.y, 16, 64); acc.y += __shfl_xor(acc.y, 32, 64);
    acc.z += __shfl_xor(acc.z, 16, 64); acc.z += __shfl_xor(acc.z, 32, 64);
    acc.w += __shfl_xor(acc.w, 16, 64); acc.w += __shfl_xor(acc.w, 32, 64);
    if (sub == 0) {
        if (OUT16) {
            __half2 a = __float22half2_rn(make_float2(acc.x, acc.y));
            __half2 b = __float22half2_rn(make_float2(acc.z, acc.w));
            uint2 w; w.x = *(unsigned*)&a; w.y = *(unsigned*)&b;
            ((uint2*)(out16 + (long long)node * 64))[q] = w;
        } else {
            *(float4*)(out32 + (long long)node * 64 + q * 4) = acc;
        }
    }
}

// ---- fused tail: softmax -> fc1 -> fusion gate; bn applied to hidden --------
#define TPAD 68
__device__ __forceinline__ float dot4(float4 a, float4 b) {
    return fmaf(a.x, b.x, fmaf(a.y, b.y, fmaf(a.z, b.z, a.w * b.w)));
}

__global__ __launch_bounds__(256) void tail_kernel(const float* __restrict__ x2,
                                                   const float* __restrict__ h2raw,
                                                   const float* __restrict__ fc1_W,
                                                   const float* __restrict__ fusW1,
                                                   const float* __restrict__ b1,
                                                   const float* __restrict__ w2,
                                                   const float* __restrict__ b2,
                                                   const float* __restrict__ stats,
                                                   const float* __restrict__ gamma,
                                                   const float* __restrict__ beta,
                                                   float invN,
                                                   float* __restrict__ out, int n) {
    __shared__ float A[64 * TPAD];    // P (softmax probs), later S (subn)
    __shared__ float Hs[64 * TPAD];   // hidden tile (bn applied)
    __shared__ float WL[64 * TPAD];   // fc1_W, later fus_l1_W
    __shared__ float bsc[64], bsh[64];
    int t = threadIdx.x;
    int tx = t & 15, ty = t >> 4;
    int r0 = blockIdx.x * 64;

    if (t < 64) {
        float mu = stats[t] * invN;
        float var = stats[64 + t] * invN - mu * mu;
        float s = gamma[t] * rsqrtf(var + 1e-5f);
        bsc[t] = s; bsh[t] = beta[t] - mu * s;
    }
    __syncthreads();

    float b1d[4], w2d[4];
#pragma unroll
    for (int di = 0; di < 4; ++di) {
        b1d[di] = b1[tx + 16 * di];
        w2d[di] = w2[tx + 16 * di];
    }
    float b20 = b2[0];

    for (int f = t; f < 1024; f += 256) {
        int d = f >> 4, k4 = (f & 15) << 2;
        *(float4*)&WL[d * TPAD + k4] = *(const float4*)&fc1_W[d * 64 + k4];
        int gr = r0 + d;
        float4 hv = make_float4(0.f, 0.f, 0.f, 0.f);
        if (gr < n) {
            hv = *(const float4*)&h2raw[(long long)gr * 64 + k4];
            hv.x = fmaf(hv.x, bsc[k4],     bsh[k4]);
            hv.y = fmaf(hv.y, bsc[k4 + 1], bsh[k4 + 1]);
            hv.z = fmaf(hv.z, bsc[k4 + 2], bsh[k4 + 2]);
            hv.w = fmaf(hv.w, bsc[k4 + 3], bsh[k4 + 3]);
        }
        *(float4*)&Hs[d * TPAD + k4] = hv;
    }

#pragma unroll
    for (int ri = 0; ri < 4; ++ri) {
        int rl = 4 * ty + ri;
        int r = r0 + rl;
        bool ok = r < n;
        float vv[4];
#pragma unroll
        for (int di = 0; di < 4; ++di)
            vv[di] = ok ? x2[(long long)r * 64 + tx + 16 * di] : 0.f;
        float m = fmaxf(fmaxf(vv[0], vv[1]), fmaxf(vv[2], vv[3]));
        for (int s = 1; s < 16; s <<= 1) m = fmaxf(m, __shfl_xor(m, s, 16));
        float e0 = expf(vv[0] - m), e1 = expf(vv[1] - m);
        float e2 = expf(vv[2] - m), e3 = expf(vv[3] - m);
        float sm = e0 + e1 + e2 + e3;
        for (int s = 1; s < 16; s <<= 1) sm += __shfl_xor(sm, s, 16);
        float inv = 1.0f / sm;
        A[rl * TPAD + tx]      = e0 * inv;
        A[rl * TPAD + tx + 16] = e1 * inv;
        A[rl * TPAD + tx + 32] = e2 * inv;
        A[rl * TPAD + tx + 48] = e3 * inv;
    }
    __syncthreads();

    float sn[4][4];
#pragma unroll
    for (int ri = 0; ri < 4; ++ri)
#pragma unroll
        for (int di = 0; di < 4; ++di) sn[ri][di] = 0.f;
    for (int k = 0; k < 64; k += 4) {
        float4 p4[4], w4[4];
#pragma unroll
        for (int ri = 0; ri < 4; ++ri) p4[ri] = *(float4*)&A[(4 * ty + ri) * TPAD + k];
#pragma unroll
        for (int di = 0; di < 4; ++di) w4[di] = *(float4*)&WL[(tx + 16 * di) * TPAD + k];
#pragma unroll
        for (int ri = 0; ri < 4; ++ri)
#pragma unroll
            for (int di = 0; di < 4; ++di)
                sn[ri][di] += dot4(p4[ri], w4[di]);
    }
    __syncthreads();

#pragma unroll
    for (int ri = 0; ri < 4; ++ri)
#pragma unroll
        for (int di = 0; di < 4; ++di)
            A[(4 * ty + ri) * TPAD + tx + 16 * di] = sn[ri][di];
    for (int f = t; f < 1024; f += 256) {
        int d = f >> 4, k4 = (f & 15) << 2;
        *(float4*)&WL[d * TPAD + k4] = *(const float4*)&fusW1[d * 64 + k4];
    }
    __syncthreads();

    float aH[4][4], aS[4][4];
#pragma unroll
    for (int ri = 0; ri < 4; ++ri)
#pragma unroll
        for (int di = 0; di < 4; ++di) { aH[ri][di] = b1d[di]; aS[ri][di] = b1d[di]; }
    for (int k = 0; k < 64; k += 4) {
        float4 h4[4], s4[4], w4[4];
#pragma unroll
        for (int ri = 0; ri < 4; ++ri) {
            h4[ri] = *(float4*)&Hs[(4 * ty + ri) * TPAD + k];
            s4[ri] = *(float4*)&A[(4 * ty + ri) * TPAD + k];
        }
#pragma unroll
        for (int di = 0; di < 4; ++di) w4[di] = *(float4*)&WL[(tx + 16 * di) * TPAD + k];
#pragma unroll
        for (int ri = 0; ri < 4; ++ri)
#pragma unroll
            for (int di = 0; di < 4; ++di) {
                aH[ri][di] += dot4(h4[ri], w4[di]);
                aS[ri][di] += dot4(s4[ri], w4[di]);
            }
    }

#pragma unroll
    for (int ri = 0; ri < 4; ++ri) {
        int rl = 4 * ty + ri;
        int r = r0 + rl;
        float pH = 0.f, pS = 0.f;
#pragma unroll
        for (int di = 0; di < 4; ++di) {
            pH = fmaf(tanhf(aH[ri][di]), w2d[di], pH);
            pS = fmaf(tanhf(aS[ri][di]), w2d[di], pS);
        }
        for (int s = 1; s < 16; s <<= 1) {
            pH += __shfl_xor(pH, s, 16);
            pS += __shfl_xor(pS, s, 16);
        }
        pH += b20; pS += b20;
        float mx = fmaxf(pH, pS);
        float eH = expf(pH - mx), eS = expf(pS - mx);
        float inv = 1.0f / (eH + eS);
        if (r < n) {
#pragma unroll
            for (int di = 0; di < 4; ++di) {
                int d = tx + 16 * di;
                float hv = Hs[rl * TPAD + d];
                out[(long long)r * 64 + d] = (eH * hv + eS * sn[ri][di]) * inv;
            }
        }
    }
}

// ---------------------------------------------------------------------------
extern "C" void kernel_launch(void* const* d_in, const int* in_sizes, int n_in,
                              void* d_out, int out_size, void* d_ws, size_t ws_size,
                              hipStream_t stream) {
    const float* emb       = (const float*)d_in[0];
    const float* W1        = (const float*)d_in[1];
    const float* b1        = (const float*)d_in[2];
    const float* W2        = (const float*)d_in[3];
    const float* b2        = (const float*)d_in[4];
    const float* gamma     = (const float*)d_in[5];
    const float* beta      = (const float*)d_in[6];
    const float* hgc1_bias = (const float*)d_in[7];
    const float* fc1_W     = (const float*)d_in[8];
    const float* fus_l1_W  = (const float*)d_in[9];
    const float* fus_l1_b  = (const float*)d_in[10];
    const float* fus_l2_W  = (const float*)d_in[11];
    const float* fus_l2_b  = (const float*)d_in[12];
    const float* hg_val    = (const float*)d_in[13];
    const int*   edge_index= (const int*)d_in[14];
    const int*   hg_row    = (const int*)d_in[15];
    const int*   hg_col    = (const int*)d_in[16];

    const int N   = in_sizes[0] / 64;
    const int E   = in_sizes[14] / 2;
    const int NNZ = in_sizes[13];
    const int Np  = (N + 3) & ~3;            // 16B-aligned strides
    const int keyspan = (N + SEGS - 1) / SEGS;
    const int PB = (N + SCHUNK - 1) / SCHUNK;   // scan blocks per array (<=64)
    const int* src = edge_index;
    const int* dst = edge_index + E;

    // workspace layout (4B units):
    // dinv Np | sdi Np | w12 4096 | bw 64 |
    // Z: [stats 128 | gcn_cnt Np | hgc_cnt Np | hgr_cnt Np]  <- single memset
    // gcn_off Np+4 | hgc_off Np+4 | hgr_off Np+4 | partials 192 |
    // gcn_srcs E/2 (u16) | hgc_ent NNZ | hgr_ent NNZ |
    // hbufA 32Np (emb16 -> xre16) | hbufB 32Np (tbuf16 -> eemb16) |
    // fbufA 64Np (ubuf -> x2) | h2 64Np
    float* ws      = (float*)d_ws;
    float* dinv    = ws;
    float* sdi     = dinv + Np;
    float* w12     = sdi + Np;
    float* bw      = w12 + 4096;
    float* stats   = bw + 64;
    int*   gcn_cnt = (int*)(stats + 128);
    int*   hgc_cnt = gcn_cnt + Np;
    int*   hgr_cnt = hgc_cnt + Np;
    int*   gcn_off = hgr_cnt + Np;
    int*   hgc_off = gcn_off + (Np + 4);
    int*   hgr_off = hgc_off + (Np + 4);
    int*   partials= hgr_off + (Np + 4);
    unsigned short* gcn_srcs = (unsigned short*)(partials + 192);
    unsigned* hgc_ent = (unsigned*)(gcn_srcs + ((E + 1) & ~1));
    unsigned* hgr_ent = hgc_ent + NNZ;
    __half* hbufA  = (__half*)(hgr_ent + NNZ);
    __half* hbufB  = hbufA + (size_t)64 * Np;
    float*  fbufA  = (float*)(hbufB + (size_t)64 * Np);
    float*  h2     = fbufA + (size_t)64 * Np;

    __half* emb16  = hbufA;    // cast of emb        N x 64 f16
    __half* tbuf16 = hbufB;    // A-hat emb          N x 64 f16
    float*  ubuf   = fbufA;    // A-hat^2 emb        N x 64 f32
    __half* xre16  = hbufA;    // relu(bn)+bias      N x 64 f16 (emb16 dead)
    __half* eemb16 = hbufB;    // edge emb           N x 64 f16 (tbuf16 dead)
    float*  x2     = fbufA;    // HGNN out           N x 64 f32 (ubuf dead)
    float*  out    = (float*)d_out;

    const float invN = 1.0f / (float)N;
    const int total4 = N * 16;

    // --- CSR builds (XCD-local segmented; decoupled scan) ---
    hipMemsetAsync(stats, 0, (size_t)(128 + 3 * Np) * sizeof(int), stream);
    hist_all_kernel<<<SEGS * SEGBLK, 256, 0, stream>>>(dst, E, hg_row, hg_col, NNZ,
                                                       gcn_cnt, hgr_cnt, hgc_cnt, keyspan);
    scan_part_kernel<<<3 * PB, 256, 0, stream>>>(gcn_cnt, hgc_cnt, hgr_cnt, partials, N, PB);
    scan_apply_kernel<<<3 * PB, 256, 0, stream>>>(gcn_cnt, gcn_off, hgc_cnt, hgc_off,
                                                  hgr_cnt, hgr_off, partials, dinv, N, PB);
    place_all_kernel<<<SEGS * SEGBLK, 256, 0, stream>>>(src, dst, gcn_cnt, gcn_srcs, E,
                                                        hg_row, hg_col, hg_val,
                                                        hgc_cnt, hgr_cnt,
                                                        hgc_ent, hgr_ent, NNZ, keyspan);

    // --- weight precompute + fp16 cast + reassociated GCN ---
    wprep_kernel<<<65, 64, 0, stream>>>(W1, W2, b1, w12, bw);
    conv16_kernel<<<(total4 + 255) / 256, 256, 0, stream>>>(emb, emb16, total4);
    gcn_gather16_kernel<true, true><<<(N + 3) / 4, 256, 0, stream>>>(
        emb16, dinv, gcn_off, gcn_srcs, tbuf16, nullptr, sdi, N);
    gcn_gather16_kernel<false, false><<<(N + 3) / 4, 256, 0, stream>>>(
        tbuf16, dinv, gcn_off, gcn_srcs, nullptr, ubuf, nullptr, N);
    gemm_h2_kernel<<<(N + 31) / 32, 256, 0, stream>>>(ubuf, w12, bw, b2, sdi, h2, stats, N);

    // --- bn+relu+bias -> fp16, then HGNN gathers on fp16 rows ---
    bn_apply16_kernel<<<(total4 + 255) / 256, 256, 0, stream>>>(h2, stats, gamma, beta,
                                                                hgc1_bias, invN, xre16, total4);
    hg_gather16_kernel<true><<<(N + 3) / 4, 256, 0, stream>>>(xre16, hgc_off, hgc_ent,
                                                              eemb16, nullptr, N);
    hg_gather16_kernel<false><<<(N + 3) / 4, 256, 0, stream>>>(eemb16, hgr_off, hgr_ent,
                                                               nullptr, x2, N);

    // --- fused softmax + fc1 + fusion gate (bn on hidden inline) ---
    tail_kernel<<<(N + 63) / 64, 256, 0, stream>>>(x2, h2, fc1_W, fus_l1_W, fus_l1_b,
                                                   fus_l2_W, fus_l2_b, stats, gamma, beta,
                                                   invN, out, N);
}